// Round 1
// baseline (529.449 us; speedup 1.0000x reference)
//
#include <hip/hip_runtime.h>
#include <math.h>

#define EMBED 1024
#define HIDDEN 128
#define NPROTO 512

typedef short bf16x8 __attribute__((ext_vector_type(8)));
typedef float f32x4 __attribute__((ext_vector_type(4)));

__device__ __forceinline__ unsigned short f2bf(float x) {
    unsigned u = __builtin_bit_cast(unsigned, x);
    unsigned r = u + 0x7FFFu + ((u >> 16) & 1u);   // round-to-nearest-even
    return (unsigned short)(r >> 16);
}

// Prep: blocks 0..255  -> proto_h[2b], proto_h[2b+1]  (fp32 GEMV, K=1024)
//       blocks 256..319 -> w1t = bf16(W1[0:1024])^T, [n][k] layout, bf16x8 writes
__global__ __launch_bounds__(256) void prep_kernel(
    const float* __restrict__ prototypes,   // [512][1024]
    const float* __restrict__ W1,           // [2048][128]
    float* __restrict__ proto_h,            // ws [512][128]
    unsigned short* __restrict__ w1t)       // ws [128][1024] bf16
{
    int b = blockIdx.x;
    int t = threadIdx.x;
    if (b < 256) {
        int ph = t >> 7, h = t & 127;
        int p = b * 2 + ph;
        const float* pr = prototypes + (size_t)p * EMBED;
        const float* w  = W1 + (size_t)EMBED * HIDDEN + h;   // W1 bottom half, col h
        float acc = 0.f;
        for (int k = 0; k < EMBED; k += 8) {
            #pragma unroll
            for (int j = 0; j < 8; ++j)
                acc += pr[k + j] * w[(size_t)(k + j) * HIDDEN];
        }
        proto_h[(size_t)p * HIDDEN + h] = acc;
    } else {
        int s = (b - 256) * 256 + t;        // 0..16383
        int n = s & 127;
        int k0 = (s >> 7) * 8;              // 0..1016
        bf16x8 v;
        #pragma unroll
        for (int j = 0; j < 8; ++j)
            v[j] = (short)f2bf(W1[(size_t)(k0 + j) * HIDDEN + n]);
        *(bf16x8*)(w1t + (size_t)n * EMBED + k0) = v;
    }
}

// Fused, wave-independent: each wave owns 32 query rows end-to-end.
//   argmin(dist row) -> MFMA GEMM (A: global f32 -> reg -> bf16, 2-deep pipeline;
//   B: w1t from L2) -> +b1 +proto_h[idx] -> relu -> dot W2 -> sigmoid.
// ZERO __syncthreads; only LDS is 512B of per-wave argmin indices.
__global__ __launch_bounds__(256, 2) void main_kernel(
    const float* __restrict__ qf,           // [65536][1024]
    const float* __restrict__ dist,         // [65536][512]
    const float* __restrict__ b1,           // [128]
    const float* __restrict__ W2,           // [128]
    const float* __restrict__ b2,           // [1]
    const float* __restrict__ proto_h,      // [512][128]
    const unsigned short* __restrict__ w1t, // [128][1024] bf16
    float* __restrict__ out)                // [65536]
{
    __shared__ int s_idx[4][32];

    const int t = threadIdx.x;
    const int wave = t >> 6, lane = t & 63;
    const int quad = lane >> 4, tid16 = lane & 15;
    const int q0 = blockIdx.x * 128 + wave * 32;   // this wave's 32 rows

    // A fragment addressing: lane reads rows q0 + mi*16 + tid16,
    // k = ks*32 + quad*8 .. +8 (f32), matching mfma_f32_16x16x32_bf16 A layout.
    const float* abase = qf + (size_t)(q0 + tid16) * EMBED + quad * 8;
    // B fragment addressing: row n = ni*16 + tid16 of w1t[n][k], same k pattern.
    const unsigned short* bbase = w1t + (size_t)tid16 * EMBED + quad * 8;

    // ---- Prologue: issue A(ks=0), A(ks=1) loads; they fly during the argmin.
    float4 aA[2][2], aB[2][2];   // two pipeline stages x {mi} x {two float4}
    #pragma unroll
    for (int mi = 0; mi < 2; ++mi) {
        const float* p = abase + (size_t)(mi * 16) * EMBED;
        aA[mi][0] = *(const float4*)(p);
        aA[mi][1] = *(const float4*)(p + 4);
        aB[mi][0] = *(const float4*)(p + 32);
        aB[mi][1] = *(const float4*)(p + 36);
    }

    // ---- Phase 1: argmin over 512 distances for this wave's 32 rows.
    for (int i = 0; i < 32; i += 4) {
        float4 v0[4], v1[4];
        #pragma unroll
        for (int j = 0; j < 4; ++j) {
            const float* dr = dist + (size_t)(q0 + i + j) * NPROTO;
            v0[j] = ((const float4*)dr)[lane];
            v1[j] = ((const float4*)dr)[lane + 64];
        }
        #pragma unroll
        for (int j = 0; j < 4; ++j) {
            float bv = v0[j].x; int bi = lane * 4;
            if (v0[j].y < bv) { bv = v0[j].y; bi = lane * 4 + 1; }
            if (v0[j].z < bv) { bv = v0[j].z; bi = lane * 4 + 2; }
            if (v0[j].w < bv) { bv = v0[j].w; bi = lane * 4 + 3; }
            int c = 256 + lane * 4;
            if (v1[j].x < bv) { bv = v1[j].x; bi = c; }
            if (v1[j].y < bv) { bv = v1[j].y; bi = c + 1; }
            if (v1[j].z < bv) { bv = v1[j].z; bi = c + 2; }
            if (v1[j].w < bv) { bv = v1[j].w; bi = c + 3; }
            #pragma unroll
            for (int s = 1; s < 64; s <<= 1) {
                float ov = __shfl_xor(bv, s);
                int   oi = __shfl_xor(bi, s);
                if (ov < bv || (ov == bv && oi < bi)) { bv = ov; bi = oi; }
            }
            if (lane == 0) s_idx[wave][i + j] = bi;
        }
    }

    // ---- Phase 2: 32xK GEMM, K=1024 in 32 steps of 32, no LDS, no barriers.
    f32x4 acc[2][8];
    #pragma unroll
    for (int mi = 0; mi < 2; ++mi)
        #pragma unroll
        for (int ni = 0; ni < 8; ++ni)
            acc[mi][ni] = (f32x4){0.f, 0.f, 0.f, 0.f};

#define LOAD_A(dst, kk)                                              \
    do {                                                             \
        _Pragma("unroll")                                            \
        for (int mi = 0; mi < 2; ++mi) {                             \
            const float* p = abase + (size_t)(mi * 16) * EMBED + (kk) * 32; \
            dst[mi][0] = *(const float4*)(p);                        \
            dst[mi][1] = *(const float4*)(p + 4);                    \
        }                                                            \
    } while (0)

#define CVT_A(af, src)                                               \
    do {                                                             \
        _Pragma("unroll")                                            \
        for (int mi = 0; mi < 2; ++mi) {                             \
            af[mi][0] = (short)f2bf(src[mi][0].x);                   \
            af[mi][1] = (short)f2bf(src[mi][0].y);                   \
            af[mi][2] = (short)f2bf(src[mi][0].z);                   \
            af[mi][3] = (short)f2bf(src[mi][0].w);                   \
            af[mi][4] = (short)f2bf(src[mi][1].x);                   \
            af[mi][5] = (short)f2bf(src[mi][1].y);                   \
            af[mi][6] = (short)f2bf(src[mi][1].z);                   \
            af[mi][7] = (short)f2bf(src[mi][1].w);                   \
        }                                                            \
    } while (0)

    for (int k = 0; k < 32; k += 2) {
        // ---- even step: consumes aA (k), prefetches aA <- k+2
        {
            bf16x8 bfr[8];                      // B(k): issued before the A-wait,
            #pragma unroll                      // L2 latency hides under cvt.
            for (int ni = 0; ni < 8; ++ni)
                bfr[ni] = *(const bf16x8*)(bbase + (size_t)(ni * 16) * EMBED + k * 32);
            bf16x8 af[2];
            CVT_A(af, aA);                      // waits only on A(k)
            if (k + 2 < 32) LOAD_A(aA, k + 2);  // 2-deep A pipeline (HBM)
            #pragma unroll
            for (int mi = 0; mi < 2; ++mi)
                #pragma unroll
                for (int ni = 0; ni < 8; ++ni)
                    acc[mi][ni] = __builtin_amdgcn_mfma_f32_16x16x32_bf16(
                        af[mi], bfr[ni], acc[mi][ni], 0, 0, 0);
        }
        // ---- odd step: consumes aB (k+1), prefetches aB <- k+3
        {
            bf16x8 bfr[8];
            #pragma unroll
            for (int ni = 0; ni < 8; ++ni)
                bfr[ni] = *(const bf16x8*)(bbase + (size_t)(ni * 16) * EMBED + (k + 1) * 32);
            bf16x8 af[2];
            CVT_A(af, aB);
            if (k + 3 < 32) LOAD_A(aB, k + 3);
            #pragma unroll
            for (int mi = 0; mi < 2; ++mi)
                #pragma unroll
                for (int ni = 0; ni < 8; ++ni)
                    acc[mi][ni] = __builtin_amdgcn_mfma_f32_16x16x32_bf16(
                        af[mi], bfr[ni], acc[mi][ni], 0, 0, 0);
        }
    }
#undef LOAD_A
#undef CVT_A

    // ---- Epilogue (wave-local): +b1 +proto_h[idx], relu, dot W2, sigmoid.
    // C layout of 16x16x32: col = tid16 (n), row = quad*4 + r (m).
    float b1v[8], w2v[8];
    #pragma unroll
    for (int ni = 0; ni < 8; ++ni) {
        b1v[ni] = b1[ni * 16 + tid16];
        w2v[ni] = W2[ni * 16 + tid16];
    }
    const float b2v = b2[0];
    #pragma unroll
    for (int mi = 0; mi < 2; ++mi) {
        #pragma unroll
        for (int r = 0; r < 4; ++r) {
            int m = mi * 16 + quad * 4 + r;
            const float* ph = proto_h + (size_t)s_idx[wave][m] * HIDDEN + tid16;
            float sum = 0.f;
            #pragma unroll
            for (int ni = 0; ni < 8; ++ni) {
                float v = acc[mi][ni][r] + b1v[ni] + ph[ni * 16];
                sum += fmaxf(v, 0.f) * w2v[ni];
            }
            #pragma unroll
            for (int s = 1; s < 16; s <<= 1) sum += __shfl_xor(sum, s);
            if (tid16 == 0) out[q0 + m] = 1.f / (1.f + expf(-(sum + b2v)));
        }
    }
}

extern "C" void kernel_launch(void* const* d_in, const int* in_sizes, int n_in,
                              void* d_out, int out_size, void* d_ws, size_t ws_size,
                              hipStream_t stream) {
    const float* qf    = (const float*)d_in[0];   // [65536,1024]
    const float* proto = (const float*)d_in[1];   // [512,1024]
    const float* dist  = (const float*)d_in[2];   // [65536,512]
    const float* W1    = (const float*)d_in[3];   // [2048,128]
    const float* b1    = (const float*)d_in[4];   // [128]
    const float* W2    = (const float*)d_in[5];   // [128,1]
    const float* b2    = (const float*)d_in[6];   // [1]
    float* out = (float*)d_out;

    float* proto_h = (float*)d_ws;                                        // 256 KB
    unsigned short* w1t = (unsigned short*)((char*)d_ws + 512 * 128 * 4); // 256 KB

    prep_kernel<<<320, 256, 0, stream>>>(proto, W1, proto_h, w1t);

    int nq = in_sizes[0] / EMBED;  // 65536
    main_kernel<<<nq / 128, 256, 0, stream>>>(qf, dist, b1, W2, b2, proto_h, w1t, out);
}

// Round 2
// 486.678 us; speedup vs baseline: 1.0879x; 1.0879x over previous
//
#include <hip/hip_runtime.h>
#include <math.h>

#define EMBED 1024
#define HIDDEN 128
#define NPROTO 512

typedef short bf16x8 __attribute__((ext_vector_type(8)));
typedef float f32x4 __attribute__((ext_vector_type(4)));
typedef unsigned int u32x4 __attribute__((ext_vector_type(4)));

// round-half-up bf16 (same max error as RNE: 0.5 ulp; only ties differ)
__device__ __forceinline__ unsigned short f2bf(float x) {
    unsigned u = __builtin_bit_cast(unsigned, x);
    return (unsigned short)((u + 0x8000u) >> 16);
}
__device__ __forceinline__ unsigned pk2(float a, float b) {
    unsigned ua = __builtin_bit_cast(unsigned, a) + 0x8000u;
    unsigned ub = __builtin_bit_cast(unsigned, b) + 0x8000u;
    return (ua >> 16) | (ub & 0xFFFF0000u);
}

#define GLL16(gptr, lptr)                                                \
    __builtin_amdgcn_global_load_lds(                                    \
        (const __attribute__((address_space(1))) void*)(gptr),           \
        (__attribute__((address_space(3))) void*)(lptr), 16, 0, 0)

// Prep: blocks 0..511   -> proto_h[b]  (fp32 GEMV, 2-way K-split)
//       blocks 512..575 -> w1t = bf16(W1[0:1024])^T, [n][k] layout
__global__ __launch_bounds__(256) void prep_kernel(
    const float* __restrict__ prototypes,   // [512][1024]
    const float* __restrict__ W1,           // [2048][128]
    float* __restrict__ proto_h,            // ws [512][128]
    unsigned short* __restrict__ w1t)       // ws [128][1024] bf16
{
    int b = blockIdx.x;
    int t = threadIdx.x;
    if (b < 512) {
        __shared__ float s_part[128];
        int ks = t >> 7, h = t & 127;
        const float* pr = prototypes + (size_t)b * EMBED + ks * 512;
        const float* w  = W1 + (size_t)(EMBED + ks * 512) * HIDDEN + h;
        float acc = 0.f;
        for (int k = 0; k < 512; k += 8) {
            #pragma unroll
            for (int j = 0; j < 8; ++j)
                acc += pr[k + j] * w[(size_t)(k + j) * HIDDEN];
        }
        if (ks) s_part[h] = acc;
        __syncthreads();
        if (!ks) proto_h[(size_t)b * HIDDEN + h] = acc + s_part[h];
    } else {
        int s = (b - 512) * 256 + t;        // 0..16383
        int n = s & 127;
        int k0 = (s >> 7) * 8;              // 0..1016
        bf16x8 v;
        #pragma unroll
        for (int j = 0; j < 8; ++j)
            v[j] = (short)f2bf(W1[(size_t)(k0 + j) * HIDDEN + n]);
        *(bf16x8*)(w1t + (size_t)n * EMBED + k0) = v;
    }
}

// Fused: argmin -> MFMA GEMM with async global_load_lds staging (depth-3,
// counted vmcnt, raw s_barrier) -> +proto_h[idx] +b1 -> relu -> dot W2 -> sigmoid.
// Block: 256 thr / 4 waves / 128 rows. Wave w computes rows w*32..w*32+31 x all 128 n.
// LDS per tile: A = 128x32 f32 (16KB, quad-plane + XOR-half swizzle),
//               B = 4 k-planes x 128n x 16B (8KB). 3 buffers = 72KB -> 2 blocks/CU.
__global__ __launch_bounds__(256, 2) void main_kernel(
    const float* __restrict__ qf,           // [65536][1024]
    const float* __restrict__ dist,         // [65536][512]
    const float* __restrict__ b1,           // [128]
    const float* __restrict__ W2,           // [128]
    const float* __restrict__ b2,           // [1]
    const float* __restrict__ proto_h,      // [512][128]
    const unsigned short* __restrict__ w1t, // [128][1024] bf16
    float* __restrict__ out)                // [65536]
{
    __shared__ __align__(16) char lds_a[3][16384];
    __shared__ __align__(16) char lds_b[3][8192];
    __shared__ int s_idx[4][32];

    const int t = threadIdx.x;
    const int wave = t >> 6, lane = t & 63;
    const int quad = lane >> 4, tid16 = lane & 15;
    const int q0  = blockIdx.x * 128;
    const int q0w = q0 + wave * 32;

    // ---- staging source addresses (tile 0), per lane ----
    // A chunk i: LDS linear pos = chunk*1024 + lane*16 decodes to
    //   plane p=wave, row = i*32 + (lane>>1), half = lane&1.
    //   Stored data = logical half (lane&1)^((row>>2)&1)  [XOR swizzle on source]
    const char* gA[4];
    {
        int rsub = lane >> 1;                              // 0..31
        int hlog = (lane & 1) ^ ((lane >> 3) & 1);         // (row>>2)&1 == (lane>>3)&1
        #pragma unroll
        for (int i = 0; i < 4; ++i) {
            int row = i * 32 + rsub;
            gA[i] = (const char*)(qf + (size_t)(q0 + row) * EMBED + wave * 8 + hlog * 4);
        }
    }
    // B chunk i: wave stages k-plane s=wave; n = i*64 + lane
    const char* gB[2];
    #pragma unroll
    for (int i = 0; i < 2; ++i)
        gB[i] = (const char*)(w1t + (size_t)(i * 64 + lane) * EMBED + wave * 8);

#define STAGE(buf) do {                                                  \
        char* la_ = &lds_a[buf][(wave * 4) * 1024];                      \
        char* lb_ = &lds_b[buf][(wave * 2) * 1024];                      \
        _Pragma("unroll")                                                \
        for (int i_ = 0; i_ < 4; ++i_) {                                 \
            GLL16(gA[i_], la_ + i_ * 1024); gA[i_] += 128;               \
        }                                                                \
        _Pragma("unroll")                                                \
        for (int i_ = 0; i_ < 2; ++i_) {                                 \
            GLL16(gB[i_], lb_ + i_ * 1024); gB[i_] += 64;                \
        }                                                                \
    } while (0)

    // ---- Prologue: issue tiles 0,1 (48KB/block in flight during argmin) ----
    STAGE(0);
    STAGE(1);

    // ---- Phase 1: argmin, distance-2 rotating 3-set register pipeline ----
#define AMLD(st, base) do {                                              \
        _Pragma("unroll")                                                \
        for (int j_ = 0; j_ < 4; ++j_) {                                 \
            const float* dr_ = dist + (size_t)(q0w + (base) + j_) * NPROTO; \
            st[2 * j_]     = ((const float4*)dr_)[lane];                 \
            st[2 * j_ + 1] = ((const float4*)dr_)[lane + 64];            \
        }                                                                \
    } while (0)
#define AMPROC(st, base) do {                                            \
        _Pragma("unroll")                                                \
        for (int j_ = 0; j_ < 4; ++j_) {                                 \
            float4 v0 = st[2 * j_], v1 = st[2 * j_ + 1];                 \
            float bv = v0.x; int bi = lane * 4;                          \
            if (v0.y < bv) { bv = v0.y; bi = lane * 4 + 1; }             \
            if (v0.z < bv) { bv = v0.z; bi = lane * 4 + 2; }             \
            if (v0.w < bv) { bv = v0.w; bi = lane * 4 + 3; }             \
            int c_ = 256 + lane * 4;                                     \
            if (v1.x < bv) { bv = v1.x; bi = c_; }                       \
            if (v1.y < bv) { bv = v1.y; bi = c_ + 1; }                   \
            if (v1.z < bv) { bv = v1.z; bi = c_ + 2; }                   \
            if (v1.w < bv) { bv = v1.w; bi = c_ + 3; }                   \
            _Pragma("unroll")                                            \
            for (int s_ = 1; s_ < 64; s_ <<= 1) {                        \
                float ov = __shfl_xor(bv, s_);                           \
                int   oi = __shfl_xor(bi, s_);                           \
                if (ov < bv || (ov == bv && oi < bi)) { bv = ov; bi = oi; } \
            }                                                            \
            if (lane == 0) s_idx[wave][(base) + j_] = bi;                \
        }                                                                \
    } while (0)

    {
        float4 A0[8], A1[8], A2[8];
        AMLD(A0, 0);  AMLD(A1, 4);
        AMLD(A2, 8);  AMPROC(A0, 0);
        AMLD(A0, 12); AMPROC(A1, 4);
        AMLD(A1, 16); AMPROC(A2, 8);
        AMLD(A2, 20); AMPROC(A0, 12);
        AMLD(A0, 24); AMPROC(A1, 16);
        AMLD(A1, 28); AMPROC(A2, 20);
        AMPROC(A0, 24);
        AMPROC(A1, 28);
    }

    // ---- Phase 2: GEMM over K=1024, BK=32, 32 tiles, depth-3 async pipe ----
    f32x4 acc[2][8];
    #pragma unroll
    for (int mi = 0; mi < 2; ++mi)
        #pragma unroll
        for (int ni = 0; ni < 8; ++ni)
            acc[mi][ni] = (f32x4){0.f, 0.f, 0.f, 0.f};

    // A frag read: logical half h at  aoff ^ (h*16)  (source-side XOR swizzle)
    const int aoff = quad * 4096 + (wave * 32 + tid16) * 32 + ((tid16 >> 2) & 1) * 16;
    const int boff = quad * 2048 + tid16 * 16;

#define COMPUTE(buf) do {                                                \
        bf16x8 bfr[8];                                                   \
        _Pragma("unroll")                                                \
        for (int ni_ = 0; ni_ < 8; ++ni_)                                \
            bfr[ni_] = *(const bf16x8*)(&lds_b[buf][boff + ni_ * 256]);  \
        _Pragma("unroll")                                                \
        for (int mi_ = 0; mi_ < 2; ++mi_) {                              \
            float4 lo = *(const float4*)(&lds_a[buf][aoff + mi_ * 512]); \
            float4 hi = *(const float4*)(&lds_a[buf][(aoff ^ 16) + mi_ * 512]); \
            u32x4 p_;                                                    \
            p_.x = pk2(lo.x, lo.y); p_.y = pk2(lo.z, lo.w);              \
            p_.z = pk2(hi.x, hi.y); p_.w = pk2(hi.z, hi.w);              \
            bf16x8 af = __builtin_bit_cast(bf16x8, p_);                  \
            _Pragma("unroll")                                            \
            for (int ni_ = 0; ni_ < 8; ++ni_)                            \
                acc[mi_][ni_] = __builtin_amdgcn_mfma_f32_16x16x32_bf16( \
                    af, bfr[ni_], acc[mi_][ni_], 0, 0, 0);               \
        }                                                                \
    } while (0)

    int bufr = 0, bufs = 2;
    for (int kt = 0; kt < 31; ++kt) {
        // wait: tile kt staged (6 newest ops = tile kt+1); sync all waves' chunks
        asm volatile("s_waitcnt vmcnt(6)\n\ts_barrier" ::: "memory");
        if (kt < 30) {                       // issue tile kt+2 (buffer of kt-1)
            STAGE(bufs);
            bufs = (bufs == 2) ? 0 : bufs + 1;
        }
        COMPUTE(bufr);
        bufr = (bufr == 2) ? 0 : bufr + 1;
    }
    asm volatile("s_waitcnt vmcnt(0)\n\ts_barrier" ::: "memory");
    COMPUTE(bufr);

    // ---- Epilogue (wave-local): +b1 +proto_h[idx], relu, dot W2, sigmoid ----
    float b1v[8], w2v[8];
    #pragma unroll
    for (int ni = 0; ni < 8; ++ni) {
        b1v[ni] = b1[ni * 16 + tid16];
        w2v[ni] = W2[ni * 16 + tid16];
    }
    const float b2v = b2[0];
    #pragma unroll
    for (int mi = 0; mi < 2; ++mi) {
        #pragma unroll
        for (int r = 0; r < 4; ++r) {
            int m = mi * 16 + quad * 4 + r;
            const float* ph = proto_h + (size_t)s_idx[wave][m] * HIDDEN + tid16;
            float sum = 0.f;
            #pragma unroll
            for (int ni = 0; ni < 8; ++ni) {
                float v = acc[mi][ni][r] + b1v[ni] + ph[ni * 16];
                sum += fmaxf(v, 0.f) * w2v[ni];
            }
            #pragma unroll
            for (int s = 1; s < 16; s <<= 1) sum += __shfl_xor(sum, s);
            if (tid16 == 0) out[q0w + m] = 1.f / (1.f + expf(-(sum + b2v)));
        }
    }
#undef STAGE
#undef AMLD
#undef AMPROC
#undef COMPUTE
}

extern "C" void kernel_launch(void* const* d_in, const int* in_sizes, int n_in,
                              void* d_out, int out_size, void* d_ws, size_t ws_size,
                              hipStream_t stream) {
    const float* qf    = (const float*)d_in[0];   // [65536,1024]
    const float* proto = (const float*)d_in[1];   // [512,1024]
    const float* dist  = (const float*)d_in[2];   // [65536,512]
    const float* W1    = (const float*)d_in[3];   // [2048,128]
    const float* b1    = (const float*)d_in[4];   // [128]
    const float* W2    = (const float*)d_in[5];   // [128,1]
    const float* b2    = (const float*)d_in[6];   // [1]
    float* out = (float*)d_out;

    float* proto_h = (float*)d_ws;                                        // 256 KB
    unsigned short* w1t = (unsigned short*)((char*)d_ws + 512 * 128 * 4); // 256 KB

    prep_kernel<<<576, 256, 0, stream>>>(proto, W1, proto_h, w1t);

    int nq = in_sizes[0] / EMBED;  // 65536
    main_kernel<<<nq / 128, 256, 0, stream>>>(qf, dist, b1, W2, b2, proto_h, w1t, out);
}